// Round 15
// baseline (316.640 us; speedup 1.0000x reference)
//
#include <hip/hip_runtime.h>
#include <hip/hip_bf16.h>
#include <stdint.h>

// MLAAttention on MI355X (gfx950).
// B=4 T=4096 D=1024 H=16 M=64 Dh=64. All inputs f32 (mask int32), output f32.
// R15: GEMM -> 128x128 tile, BK=64, XOR-swizzle (R8), 2-phase counted vmcnt(8),
//      64KB LDS -> 2 blocks/CU. Tests the unexplored quadrant: conflict-free
//      LDS + multi-block residency (R12's occupancy test was confounded by an
//      8-way read conflict; R8/R14's swizzled config was 1 block/CU).
//      denom_inv folded into latreduce2.

#define DEV static __device__ __forceinline__

using short8 = __attribute__((ext_vector_type(8))) short;
using f32x4  = __attribute__((ext_vector_type(4))) float;

#define ZERO4 (f32x4){0.f, 0.f, 0.f, 0.f}

DEV float bf2f(unsigned short u) {
  union { unsigned int i; float f; } c; c.i = ((unsigned int)u) << 16; return c.f;
}
DEV unsigned short f2bf(float f) {
  __hip_bfloat16 h = __float2bfloat16(f);
  unsigned short u; __builtin_memcpy(&u, &h, 2); return u;
}
DEV f32x4 mfma16(short8 a, short8 b, f32x4 c) {
  return __builtin_amdgcn_mfma_f32_16x16x32_bf16(a, b, c, 0, 0, 0);
}
#define GLOAD_LDS16(G, L) __builtin_amdgcn_global_load_lds( \
    (const __attribute__((address_space(1))) void*)(G),     \
    (__attribute__((address_space(3))) void*)(L), 16, 0, 0)

// ---------------------------------------------------------------- fused convert
__global__ void cvt_all(const float* __restrict__ x,
                        const float* __restrict__ Wq, const float* __restrict__ Wk,
                        const float* __restrict__ Wv, const float* __restrict__ Wo,
                        __hip_bfloat16* __restrict__ xb,
                        __hip_bfloat16* __restrict__ Wb) {
  const int bid = blockIdx.x;
  const float* src;
  __hip_bfloat16* dst;
  int base;
  if (bid < 16384) {
    src = x; dst = xb; base = bid;
  } else {
    const int k = (bid - 16384) >> 10;
    src = (k == 0) ? Wq : (k == 1) ? Wk : (k == 2) ? Wv : Wo;
    dst = Wb + (size_t)k * 1048576;
    base = (bid - 16384) & 1023;
  }
  const int i = (base * 256 + threadIdx.x) * 4;
  const float4 v = *(const float4*)(src + i);
  ushort4 o;
  o.x = f2bf(v.x); o.y = f2bf(v.y); o.z = f2bf(v.z); o.w = f2bf(v.w);
  *(ushort4*)(dst + i) = o;
}

// ---------------------------------------------------------------- shared GEMM core
// 128x128 tile, BK=64, 4 waves (2M x 2N), 2-phase dbuf, counted vmcnt(8),
// XOR-swizzled LDS: element (row, chunk c of 8 bf16) at (row, c ^ (row&7)).
// Linear gload_lds dest + pre-swizzled global source (staging row&7 = l>>3);
// read back with chunk ^ (lr&7). 64KB LDS -> 2 blocks/CU.
#define GEMM_CORE(A_, B_, K_)                                                     \
  __shared__ __hip_bfloat16 As[2][128 * 64];                                      \
  __shared__ __hip_bfloat16 Bs[2][128 * 64];                                      \
  const int tid = threadIdx.x;                                                    \
  const int w = tid >> 6, l = tid & 63;                                           \
  const int lr = l & 15, lg = l >> 4;                                             \
  const int rowA0 = blockIdx.x * 128;                                             \
  const int colB0 = blockIdx.y * 128;                                             \
  const int srow = w * 8 + (l >> 3);                                              \
  const int skk  = (((l & 7) ^ (l >> 3)) * 8);                                    \
  const __hip_bfloat16* Ab = A_ + (size_t)(rowA0 + srow) * K_ + skk;              \
  const __hip_bfloat16* Bb = B_ + (size_t)(colB0 + srow) * K_ + skk;              \
  f32x4 acc[4][4];                                                                \
  _Pragma("unroll")                                                               \
  for (int i = 0; i < 4; ++i)                                                     \
    _Pragma("unroll")                                                             \
    for (int j = 0; j < 4; ++j) acc[i][j] = ZERO4;                                \
  const int wr = (w >> 1) * 64;                                                   \
  const int wc = (w & 1) * 64;                                                    \
  const int NT = K_ >> 6;                                                         \
  {                                                                               \
    _Pragma("unroll")                                                             \
    for (int i = 0; i < 4; ++i) {                                                 \
      GLOAD_LDS16(Ab + (size_t)(i * 32) * K_, &As[0][i * 2048 + w * 512]);        \
      GLOAD_LDS16(Bb + (size_t)(i * 32) * K_, &Bs[0][i * 2048 + w * 512]);        \
    }                                                                             \
  }                                                                               \
  for (int kt = 0; kt < NT; ++kt) {                                               \
    const int cur = kt & 1;                                                       \
    if (kt + 1 < NT) {                                                            \
      const int k0s = (kt + 1) * 64;                                              \
      _Pragma("unroll")                                                           \
      for (int i = 0; i < 4; ++i) {                                               \
        GLOAD_LDS16(Ab + (size_t)(i * 32) * K_ + k0s, &As[cur ^ 1][i * 2048 + w * 512]); \
        GLOAD_LDS16(Bb + (size_t)(i * 32) * K_ + k0s, &Bs[cur ^ 1][i * 2048 + w * 512]); \
      }                                                                           \
      asm volatile("s_waitcnt vmcnt(8)" ::: "memory");                            \
    } else {                                                                      \
      asm volatile("s_waitcnt vmcnt(0)" ::: "memory");                            \
    }                                                                             \
    __builtin_amdgcn_s_barrier();                                                 \
    __builtin_amdgcn_s_setprio(1);                                                \
    _Pragma("unroll")                                                             \
    for (int s = 0; s < 2; ++s) {                                                 \
      short8 fa[4], fb[4];                                                        \
      _Pragma("unroll")                                                           \
      for (int i = 0; i < 4; ++i)                                                 \
        fa[i] = *(const short8*)&As[cur][(wr + i * 16 + lr) * 64 +                \
                                         (((s * 4 + lg) ^ (lr & 7)) * 8)];        \
      _Pragma("unroll")                                                           \
      for (int j = 0; j < 4; ++j)                                                 \
        fb[j] = *(const short8*)&Bs[cur][(wc + j * 16 + lr) * 64 +                \
                                         (((s * 4 + lg) ^ (lr & 7)) * 8)];        \
      _Pragma("unroll")                                                           \
      for (int i = 0; i < 4; ++i)                                                 \
        _Pragma("unroll")                                                         \
        for (int j = 0; j < 4; ++j)                                               \
          acc[i][j] = mfma16(fa[i], fb[j], acc[i][j]);                            \
    }                                                                             \
    __builtin_amdgcn_s_setprio(0);                                                \
    __builtin_amdgcn_s_barrier();                                                 \
  }

// ---------------------------------------------------------------- merged QKV GEMM
// C[16384, 3072] = xb @ [Wq;Wk;Wv]^T. 128-wide col tiles, 8 per 1024-panel:
// panel = blockIdx.y >> 3: 0 (y0-7) -> q (rope, qb); 1 (y8-15) -> k (rope,
// kb + kT); 2 (y16-23) -> v (vT only). nn = col & 1023.
// Transposed layout: Ct[((m>>12)*16 + (nn>>6))*64 + (nn&63)][t = m&4095]  (bf16)
__global__ __launch_bounds__(256)
void gemm_qkv(const __hip_bfloat16* __restrict__ A,
              const __hip_bfloat16* __restrict__ Bt,   // Wb (rows 0..3071)
              __hip_bfloat16* __restrict__ qb,
              __hip_bfloat16* __restrict__ kb,
              __hip_bfloat16* __restrict__ kT,
              __hip_bfloat16* __restrict__ vT,
              const float* __restrict__ cosT, const float* __restrict__ sinT) {
  GEMM_CORE(A, Bt, 1024)
  const int r0 = rowA0 + wr + lg * 4;     // global row (m) base, +i*16+r
  const int c0 = colB0 + wc + lr;         // global col (n), +j*16
  const int panel = blockIdx.y >> 3;      // 0=q 1=k 2=v  (128-wide tiles, 8/panel)
  if (panel < 2) {                        // rope for q and k
#pragma unroll
    for (int i = 0; i < 4; ++i)
#pragma unroll
      for (int j = 0; j < 4; ++j)
#pragma unroll
        for (int r = 0; r < 4; ++r) {
          const int m = r0 + i * 16 + r;
          const int n = c0 + j * 16;
          const int t = m & 4095, d = n & 63;
          const float c = cosT[t * 64 + d];
          const float s = sinT[t * 64 + d];
          const float v = acc[i][j][r];
          const float other = __shfl_xor(v, 1, 64);
          acc[i][j][r] = v * c + ((n & 1) ? other : -other) * s;
        }
  }
  if (panel < 2) {                        // normal-layout store (qb or kb)
    __hip_bfloat16* Cn = (panel == 0) ? qb : kb;
#pragma unroll
    for (int i = 0; i < 4; ++i)
#pragma unroll
      for (int j = 0; j < 4; ++j)
#pragma unroll
        for (int r = 0; r < 4; ++r) {
          const int nn = (c0 + j * 16) & 1023;
          Cn[(size_t)(r0 + i * 16 + r) * 1024 + nn] = __float2bfloat16(acc[i][j][r]);
        }
  }
  if (panel >= 1) {                       // transposed store (kT or vT)
    __hip_bfloat16* Ct = (panel == 1) ? kT : vT;
#pragma unroll
    for (int i = 0; i < 4; ++i)
#pragma unroll
      for (int j = 0; j < 4; ++j) {
        const int m0 = r0 + i * 16;
        const int nn = (c0 + j * 16) & 1023;
        const size_t row = (size_t)(((m0 >> 12) * 16 + (nn >> 6)) * 64 + (nn & 63));
        ushort4 pk;
        pk.x = f2bf(acc[i][j][0]); pk.y = f2bf(acc[i][j][1]);
        pk.z = f2bf(acc[i][j][2]); pk.w = f2bf(acc[i][j][3]);
        *(ushort4*)&Ct[row * 4096 + (m0 & 4095)] = pk;
      }
  }
}

// ---------------------------------------------------------------- final GEMM (f32 out)
__global__ __launch_bounds__(256)
void gemm_out(const __hip_bfloat16* __restrict__ A,
              const __hip_bfloat16* __restrict__ Bt,
              float* __restrict__ Cout) {
  GEMM_CORE(A, Bt, 1024)
  const int r0 = rowA0 + wr + lg * 4;
  const int c0 = colB0 + wc + lr;
#pragma unroll
  for (int i = 0; i < 4; ++i)
#pragma unroll
    for (int j = 0; j < 4; ++j)
#pragma unroll
      for (int r = 0; r < 4; ++r)
        Cout[(size_t)(r0 + i * 16 + r) * 1024 + (c0 + j * 16)] = acc[i][j][r];
}

// ---------------------------------------------------------------- stage1: exp(S) (MFMA)
// P[bh][m][t] = exp(0.125 * sum_d latent[h][m][d]*K[b][t][h][d])  (bf16; 0 if masked)
// Max-free softmax: |logit| <~ 0.15 by construction (latent sigma=0.02).
__global__ __launch_bounds__(256)
void stage1_expS(const __hip_bfloat16* __restrict__ kmat,  // [B,T,H,64] (roped)
                 const float* __restrict__ latent,          // [H,64,64] f32
                 const int* __restrict__ mask,               // [B*T]
                 __hip_bfloat16* __restrict__ P,             // [bh][64][4096]
                 float* __restrict__ psum) {
  const int bh = blockIdx.x, chunk = blockIdx.y;
  const int b = bh >> 4, h = bh & 15;
  const int tid = threadIdx.x, w = tid >> 6, l = tid & 63;
  const int lr = l & 15, lg = l >> 4;
  short8 la[4][2];
#pragma unroll
  for (int n = 0; n < 4; ++n)
#pragma unroll
    for (int s = 0; s < 2; ++s) {
      const float* lp = &latent[((size_t)h * 64 + n * 16 + lr) * 64 + s * 32 + lg * 8];
      short8 f;
#pragma unroll
      for (int j = 0; j < 8; ++j) f[j] = (short)f2bf(lp[j]);
      la[n][s] = f;
    }
  float sm[16];
#pragma unroll
  for (int i = 0; i < 16; ++i) sm[i] = 0.f;
  for (int tile = 0; tile < 8; ++tile) {
    const int t = chunk * 512 + tile * 64 + w * 16 + lr;
    const __hip_bfloat16* kp = &kmat[((size_t)(b * 4096 + t) * 16 + h) * 64 + lg * 8];
    const short8 kb0 = *(const short8*)kp;
    const short8 kb1 = *(const short8*)(kp + 32);
    const bool live = (mask[b * 4096 + t] != 0);
    f32x4 acc[4];
#pragma unroll
    for (int n = 0; n < 4; ++n) {
      acc[n] = ZERO4;
      acc[n] = mfma16(la[n][0], kb0, acc[n]);
      acc[n] = mfma16(la[n][1], kb1, acc[n]);
    }
#pragma unroll
    for (int n = 0; n < 4; ++n)
#pragma unroll
      for (int r = 0; r < 4; ++r) {
        const float e = live ? __expf(acc[n][r] * 0.125f) : 0.f;
        const int m = n * 16 + lg * 4 + r;
        ((unsigned short*)P)[((size_t)bh * 64 + m) * 4096 + t] = f2bf(e);
        sm[n * 4 + r] += e;
      }
  }
#pragma unroll
  for (int o = 1; o < 16; o <<= 1)
#pragma unroll
    for (int i = 0; i < 16; ++i) sm[i] += __shfl_xor(sm[i], o, 64);
  if (lr == 0) {
    const size_t pb = ((size_t)(bh * 8 + chunk) * 4 + w) * 64;
#pragma unroll
    for (int n = 0; n < 4; ++n)
#pragma unroll
      for (int r = 0; r < 4; ++r)
        psum[pb + n * 16 + lg * 4 + r] = sm[n * 4 + r];
  }
}

// ---------------------------------------------------------------- latent GEMM v7
// Direct-from-global register-fragment MFMA reduction on unnormalized P.
// 16 slices of 256 t; grid (bh=64, 4); wave w covers slice blockIdx.y*4+w.
__global__ __launch_bounds__(256)
void latgemm7(const __hip_bfloat16* __restrict__ P,   // exp-logits [bh][64][4096]
              const __hip_bfloat16* __restrict__ kT,
              const __hip_bfloat16* __restrict__ vT,
              float* __restrict__ partials) {   // [slice(16)][bh][8192]
  const int bh = blockIdx.x;
  const int tid = threadIdx.x, w = tid >> 6, l = tid & 63;
  const int slice = blockIdx.y * 4 + w;
  const int lr = l & 15;            // frag row
  const int lk = (l >> 4) * 8;      // frag k-offset
  const size_t base = (size_t)bh * 64 * 4096;
  f32x4 ak[4][4], av[4][4];
#pragma unroll
  for (int i = 0; i < 4; ++i)
#pragma unroll
    for (int j = 0; j < 4; ++j) { ak[i][j] = ZERO4; av[i][j] = ZERO4; }
  for (int ks = 0; ks < 8; ++ks) {
    const int t = slice * 256 + ks * 32 + lk;
    short8 fp[4], fk[4], fv[4];
#pragma unroll
    for (int i = 0; i < 4; ++i) {
      const size_t ro = base + (size_t)(i * 16 + lr) * 4096 + t;
      fp[i] = *(const short8*)&P[ro];
      fk[i] = *(const short8*)&kT[ro];
      fv[i] = *(const short8*)&vT[ro];
    }
#pragma unroll
    for (int i = 0; i < 4; ++i)
#pragma unroll
      for (int j = 0; j < 4; ++j) {
        ak[i][j] = mfma16(fp[i], fk[j], ak[i][j]);   // C[m][d]
        av[i][j] = mfma16(fv[i], fp[j], av[i][j]);   // C[d][m]
      }
  }
  float* pk = partials + ((size_t)(slice * 64 + bh)) * 8192;
#pragma unroll
  for (int i = 0; i < 4; ++i)
#pragma unroll
    for (int j = 0; j < 4; ++j)
#pragma unroll
      for (int r = 0; r < 4; ++r) {
        const int row = i * 16 + 4 * (l >> 4) + r;
        const int col = j * 16 + lr;
        pk[(size_t)row * 64 + col]        = ak[i][j][r];
        pk[4096 + (size_t)row * 64 + col] = av[i][j][r];
      }
}

// Sum 16 slice-partials, normalize (cinv computed per block from psum) ->
// bf16 k_lat [bh][m][d], v_latT [bh][d][m]
__global__ void latreduce2(const float* __restrict__ partials,
                           const float* __restrict__ psum,
                           __hip_bfloat16* __restrict__ k_lat,
                           __hip_bfloat16* __restrict__ v_latT) {
  __shared__ float sci[64];
  const int bid = blockIdx.x;          // 2048 blocks; 32 per bh
  const int bh = bid >> 5;
  const int tid = threadIdx.x;
  if (tid < 64) {
    float s = 0.f;
#pragma unroll
    for (int c = 0; c < 32; ++c)
      s += psum[((size_t)bh * 32 + c) * 64 + tid];
    sci[tid] = 1.f / s;
  }
  __syncthreads();
  const int i = bid * 256 + tid;       // 524288 total
  const int off = i & 8191;
  float sm = 0.f;
#pragma unroll
  for (int c = 0; c < 16; ++c)
    sm += partials[((size_t)(c * 64 + bh)) * 8192 + off];
  const int m = (off < 4096) ? (off >> 6) : (off & 63);
  sm *= sci[m];
  if (off < 4096) k_lat[(size_t)bh * 4096 + off] = __float2bfloat16(sm);
  else            v_latT[(size_t)bh * 4096 + (off - 4096)] = __float2bfloat16(sm);
}

// ---------------------------------------------------------------- stage2 fused
__global__ __launch_bounds__(256)
void stage2_attn(const __hip_bfloat16* __restrict__ q,
                 const __hip_bfloat16* __restrict__ k_lat,
                 const __hip_bfloat16* __restrict__ v_latT,
                 __hip_bfloat16* __restrict__ attn) {
  __shared__ unsigned short Pl[4][16][64];
  const int bid = blockIdx.x;
  const int bh = bid >> 6, tt = (bid & 63) * 64;
  const int b = bh >> 4, h = bh & 15;
  const int tid = threadIdx.x, w = tid >> 6, l = tid & 63;
  const size_t qoff = ((size_t)(b * 4096 + tt + w * 16 + (l & 15)) * 16 + h) * 64;
  const short8 a0 = *(const short8*)&q[qoff + (l >> 4) * 8];
  const short8 a1 = *(const short8*)&q[qoff + 32 + (l >> 4) * 8];
  f32x4 att[4];
#pragma unroll
  for (int n = 0; n < 4; ++n) att[n] = ZERO4;
#pragma unroll
  for (int n = 0; n < 4; ++n) {
    const __hip_bfloat16* kl = &k_lat[((size_t)bh * 64 + n * 16 + (l & 15)) * 64];
    const short8 b0 = *(const short8*)&kl[(l >> 4) * 8];
    const short8 b1 = *(const short8*)&kl[32 + (l >> 4) * 8];
    att[n] = mfma16(a0, b0, att[n]);
    att[n] = mfma16(a1, b1, att[n]);
  }
  float p[4][4];
#pragma unroll
  for (int r = 0; r < 4; ++r) {
    const float v0 = att[0][r] * 0.125f, v1 = att[1][r] * 0.125f;
    const float v2 = att[2][r] * 0.125f, v3 = att[3][r] * 0.125f;
    float mxv = fmaxf(fmaxf(v0, v1), fmaxf(v2, v3));
#pragma unroll
    for (int o = 1; o < 16; o <<= 1) mxv = fmaxf(mxv, __shfl_xor(mxv, o, 64));
    const float e0 = __expf(v0 - mxv), e1 = __expf(v1 - mxv);
    const float e2 = __expf(v2 - mxv), e3 = __expf(v3 - mxv);
    float sum = e0 + e1 + e2 + e3;
#pragma unroll
    for (int o = 1; o < 16; o <<= 1) sum += __shfl_xor(sum, o, 64);
    const float inv = 1.f / sum;
    p[0][r] = e0 * inv; p[1][r] = e1 * inv; p[2][r] = e2 * inv; p[3][r] = e3 * inv;
  }
#pragma unroll
  for (int n = 0; n < 4; ++n)
#pragma unroll
    for (int r = 0; r < 4; ++r) {
      const int row = 4 * (l >> 4) + r;
      const int col = n * 16 + (l & 15);
      Pl[w][row][col ^ ((row & 7) << 3)] = f2bf(p[n][r]);
    }
  __syncthreads();
  const int arow = l & 15;
  const short8 pa0 = *(const short8*)&Pl[w][arow][(((l >> 4) + 0) ^ (arow & 7)) * 8];
  const short8 pa1 = *(const short8*)&Pl[w][arow][(((l >> 4) + 4) ^ (arow & 7)) * 8];
  f32x4 ov[4];
#pragma unroll
  for (int n = 0; n < 4; ++n) ov[n] = ZERO4;
#pragma unroll
  for (int n = 0; n < 4; ++n) {
    const __hip_bfloat16* vt = &v_latT[((size_t)bh * 64 + n * 16 + (l & 15)) * 64];
    const short8 b0 = *(const short8*)&vt[(l >> 4) * 8];
    const short8 b1 = *(const short8*)&vt[32 + (l >> 4) * 8];
    ov[n] = mfma16(pa0, b0, ov[n]);
    ov[n] = mfma16(pa1, b1, ov[n]);
  }
#pragma unroll
  for (int n = 0; n < 4; ++n) {
    const int d = n * 16 + (l & 15);
#pragma unroll
    for (int r = 0; r < 4; ++r) {
      const int trow = tt + w * 16 + 4 * (l >> 4) + r;
      attn[((size_t)(b * 4096 + trow) * 16 + h) * 64 + d] = __float2bfloat16(ov[n][r]);
    }
  }
}

// ---------------------------------------------------------------- launch
extern "C" void kernel_launch(void* const* d_in, const int* in_sizes, int n_in,
                              void* d_out, int out_size, void* d_ws, size_t ws_size,
                              hipStream_t stream) {
  const float* x      = (const float*)d_in[0];
  const float* Wq     = (const float*)d_in[1];
  const float* Wk     = (const float*)d_in[2];
  const float* Wv     = (const float*)d_in[3];
  const float* Wo     = (const float*)d_in[4];
  const float* latent = (const float*)d_in[5];
  const float* cosT   = (const float*)d_in[6];
  const float* sinT   = (const float*)d_in[7];
  const int*   mask   = (const int*)d_in[8];

  char* ws = (char*)d_ws;
  __hip_bfloat16* xb = (__hip_bfloat16*)ws;                        // 33.5MB (reused as P)
  __hip_bfloat16* Wb = (__hip_bfloat16*)(ws + 33554432);           // 8.4MB
  __hip_bfloat16* qb = (__hip_bfloat16*)(ws + 41943040);           // 33.5MB (reused as attn)
  __hip_bfloat16* kb = (__hip_bfloat16*)(ws + 75497472);           // 33.5MB (reused as partials)
  __hip_bfloat16* kT = (__hip_bfloat16*)(ws + 109051904);          // 33.5MB [bh*64+d][t]
  __hip_bfloat16* vT = (__hip_bfloat16*)(ws + 142606336);          // 33.5MB
  char* tail = ws + 176160768;
  float* psum = (float*)tail;                       // 131072 f
  __hip_bfloat16* k_lat  = (__hip_bfloat16*)(psum + 131072);   // 262144 bf16
  __hip_bfloat16* v_latT = k_lat + 262144;
  float* partials = (float*)kb;             // kb dead after stage1_expS; 33.5MB
  __hip_bfloat16* P    = xb;                // xb dead after projection GEMM
  __hip_bfloat16* attn = qb;                // qb dead after stage2 (in-place ok)

  cvt_all<<<20480, 256, 0, stream>>>(x, Wq, Wk, Wv, Wo, xb, Wb);

  dim3 gq(128, 24);
  gemm_qkv<<<gq, 256, 0, stream>>>(xb, Wb, qb, kb, kT, vT, cosT, sinT);

  dim3 sg(64, 8);
  stage1_expS<<<sg, 256, 0, stream>>>(kb, latent, mask, P, psum);

  dim3 lg(64, 4);
  latgemm7<<<lg, 256, 0, stream>>>(P, kT, vT, partials);
  latreduce2<<<2048, 256, 0, stream>>>(partials, psum, k_lat, v_latT);

  stage2_attn<<<4096, 256, 0, stream>>>(qb, k_lat, v_latT, attn);

  dim3 go(128, 8);
  gemm_out<<<go, 256, 0, stream>>>(attn, Wb + 3 * 1048576, (float*)d_out);
}

// Round 16
// 293.241 us; speedup vs baseline: 1.0798x; 1.0798x over previous
//
#include <hip/hip_runtime.h>
#include <hip/hip_bf16.h>
#include <stdint.h>

// MLAAttention on MI355X (gfx950).
// B=4 T=4096 D=1024 H=16 M=64 Dh=64. All inputs f32 (mask int32), output f32.
// R16: revert GEMM to R14's 256² (R15's 128² doubled FETCH: less A-reuse).
//      stage1_expS FUSED into gemm_qkv k-panel epilogue: roped K stashed into
//      the dead As/Bs LDS (wave reads only what it wrote), stage1's verified
//      MFMA loop runs in-place -> P + psum written directly; kb store deleted
//      (saves 33.5MB write + 33.5MB read + one dispatch).

#define DEV static __device__ __forceinline__

using short8 = __attribute__((ext_vector_type(8))) short;
using f32x4  = __attribute__((ext_vector_type(4))) float;

#define ZERO4 (f32x4){0.f, 0.f, 0.f, 0.f}

DEV float bf2f(unsigned short u) {
  union { unsigned int i; float f; } c; c.i = ((unsigned int)u) << 16; return c.f;
}
DEV unsigned short f2bf(float f) {
  __hip_bfloat16 h = __float2bfloat16(f);
  unsigned short u; __builtin_memcpy(&u, &h, 2); return u;
}
DEV f32x4 mfma16(short8 a, short8 b, f32x4 c) {
  return __builtin_amdgcn_mfma_f32_16x16x32_bf16(a, b, c, 0, 0, 0);
}
#define GLOAD_LDS16(G, L) __builtin_amdgcn_global_load_lds( \
    (const __attribute__((address_space(1))) void*)(G),     \
    (__attribute__((address_space(3))) void*)(L), 16, 0, 0)

// ---------------------------------------------------------------- fused convert
__global__ void cvt_all(const float* __restrict__ x,
                        const float* __restrict__ Wq, const float* __restrict__ Wk,
                        const float* __restrict__ Wv, const float* __restrict__ Wo,
                        __hip_bfloat16* __restrict__ xb,
                        __hip_bfloat16* __restrict__ Wb) {
  const int bid = blockIdx.x;
  const float* src;
  __hip_bfloat16* dst;
  int base;
  if (bid < 16384) {
    src = x; dst = xb; base = bid;
  } else {
    const int k = (bid - 16384) >> 10;
    src = (k == 0) ? Wq : (k == 1) ? Wk : (k == 2) ? Wv : Wo;
    dst = Wb + (size_t)k * 1048576;
    base = (bid - 16384) & 1023;
  }
  const int i = (base * 256 + threadIdx.x) * 4;
  const float4 v = *(const float4*)(src + i);
  ushort4 o;
  o.x = f2bf(v.x); o.y = f2bf(v.y); o.z = f2bf(v.z); o.w = f2bf(v.w);
  *(ushort4*)(dst + i) = o;
}

// ---------------------------------------------------------------- shared GEMM core
// 256x256 tile, 8 waves (2M x 4N), 2-phase dbuf, counted vmcnt(8), XOR-swizzled
// LDS (element (row, chunk c) at (row, c ^ (row&7)); linear gload_lds dest +
// pre-swizzled global source; read back with chunk ^ (lr&7)).
#define GEMM_CORE(A_, B_, K_)                                                     \
  __shared__ __hip_bfloat16 As[2][256 * 64];                                      \
  __shared__ __hip_bfloat16 Bs[2][256 * 64];                                      \
  const int tid = threadIdx.x;                                                    \
  const int w = tid >> 6, l = tid & 63;                                           \
  const int lr = l & 15, lg = l >> 4;                                             \
  const int rowA0 = blockIdx.x * 256;                                             \
  const int colB0 = blockIdx.y * 256;                                             \
  const int srow = w * 8 + (l >> 3);                                              \
  const int skk  = (((l & 7) ^ (l >> 3)) * 8);                                    \
  const __hip_bfloat16* Ab = A_ + (size_t)(rowA0 + srow) * K_ + skk;              \
  const __hip_bfloat16* Bb = B_ + (size_t)(colB0 + srow) * K_ + skk;              \
  f32x4 acc[8][4];                                                                \
  _Pragma("unroll")                                                               \
  for (int i = 0; i < 8; ++i)                                                     \
    _Pragma("unroll")                                                             \
    for (int j = 0; j < 4; ++j) acc[i][j] = ZERO4;                                \
  const int wr = (w >> 2) * 128;                                                  \
  const int wc = (w & 3) * 64;                                                    \
  const int NT = K_ >> 6;                                                         \
  {                                                                               \
    const int k0s = 0;                                                            \
    _Pragma("unroll")                                                             \
    for (int i = 0; i < 4; ++i) {                                                 \
      GLOAD_LDS16(Ab + (size_t)(i * 64) * K_ + k0s, &As[0][i * 4096 + w * 512]);  \
      GLOAD_LDS16(Bb + (size_t)(i * 64) * K_ + k0s, &Bs[0][i * 4096 + w * 512]);  \
    }                                                                             \
  }                                                                               \
  for (int kt = 0; kt < NT; ++kt) {                                               \
    const int cur = kt & 1;                                                       \
    if (kt + 1 < NT) {                                                            \
      const int k0s = (kt + 1) * 64;                                              \
      _Pragma("unroll")                                                           \
      for (int i = 0; i < 4; ++i) {                                               \
        GLOAD_LDS16(Ab + (size_t)(i * 64) * K_ + k0s, &As[cur ^ 1][i * 4096 + w * 512]); \
        GLOAD_LDS16(Bb + (size_t)(i * 64) * K_ + k0s, &Bs[cur ^ 1][i * 4096 + w * 512]); \
      }                                                                           \
      asm volatile("s_waitcnt vmcnt(8)" ::: "memory");                            \
    } else {                                                                      \
      asm volatile("s_waitcnt vmcnt(0)" ::: "memory");                            \
    }                                                                             \
    __builtin_amdgcn_s_barrier();                                                 \
    __builtin_amdgcn_s_setprio(1);                                                \
    _Pragma("unroll")                                                             \
    for (int s = 0; s < 2; ++s) {                                                 \
      short8 fa[8], fb[4];                                                        \
      _Pragma("unroll")                                                           \
      for (int i = 0; i < 8; ++i)                                                 \
        fa[i] = *(const short8*)&As[cur][(wr + i * 16 + lr) * 64 +                \
                                         (((s * 4 + lg) ^ (lr & 7)) * 8)];        \
      _Pragma("unroll")                                                           \
      for (int j = 0; j < 4; ++j)                                                 \
        fb[j] = *(const short8*)&Bs[cur][(wc + j * 16 + lr) * 64 +                \
                                         (((s * 4 + lg) ^ (lr & 7)) * 8)];        \
      _Pragma("unroll")                                                           \
      for (int i = 0; i < 8; ++i)                                                 \
        _Pragma("unroll")                                                         \
        for (int j = 0; j < 4; ++j)                                               \
          acc[i][j] = mfma16(fa[i], fb[j], acc[i][j]);                            \
    }                                                                             \
    __builtin_amdgcn_s_setprio(0);                                                \
    __builtin_amdgcn_s_barrier();                                                 \
  }

// ---------------------------------------------------------------- merged QKV GEMM
// C[16384, 3072] = xb @ [Wq;Wk;Wv]^T. 256-wide col tiles, 4 per 1024-panel:
// panel = blockIdx.y >> 2: 0 -> q (rope, qb); 1 -> k (rope, kT + FUSED stage1:
// P = exp(latent·k/8) and psum partials); 2 -> v (vT only). nn = col & 1023.
// Transposed layout: Ct[((m>>12)*16 + (nn>>6))*64 + (nn&63)][t = m&4095]  (bf16)
__global__ __launch_bounds__(512, 2)
void gemm_qkv(const __hip_bfloat16* __restrict__ A,
              const __hip_bfloat16* __restrict__ Bt,   // Wb (rows 0..3071)
              __hip_bfloat16* __restrict__ qb,
              __hip_bfloat16* __restrict__ kT,
              __hip_bfloat16* __restrict__ vT,
              const float* __restrict__ latent,         // [H,64,64] f32
              const int* __restrict__ mask,              // [B*T]
              __hip_bfloat16* __restrict__ P,            // [bh][64][4096]
              float* __restrict__ psum,                  // [bh][32][64]
              const float* __restrict__ cosT, const float* __restrict__ sinT) {
  GEMM_CORE(A, Bt, 1024)
  const int r0 = rowA0 + wr + lg * 4;     // global row (m) base, +i*16+r
  const int c0 = colB0 + wc + lr;         // global col (n), +j*16
  const int panel = blockIdx.y >> 2;      // 0=q 1=k 2=v  (256-wide tiles, 4/panel)
  if (panel < 2) {                        // rope for q and k
#pragma unroll
    for (int i = 0; i < 8; ++i)
#pragma unroll
      for (int j = 0; j < 4; ++j)
#pragma unroll
        for (int r = 0; r < 4; ++r) {
          const int m = r0 + i * 16 + r;
          const int n = c0 + j * 16;
          const int t = m & 4095, d = n & 63;
          const float c = cosT[t * 64 + d];
          const float s = sinT[t * 64 + d];
          const float v = acc[i][j][r];
          const float other = __shfl_xor(v, 1, 64);
          acc[i][j][r] = v * c + ((n & 1) ? other : -other) * s;
        }
  }
  if (panel == 0) {                       // normal-layout store (qb only)
#pragma unroll
    for (int i = 0; i < 8; ++i)
#pragma unroll
      for (int j = 0; j < 4; ++j)
#pragma unroll
        for (int r = 0; r < 4; ++r) {
          const int nn = (c0 + j * 16) & 1023;
          qb[(size_t)(r0 + i * 16 + r) * 1024 + nn] = __float2bfloat16(acc[i][j][r]);
        }
  }
  if (panel >= 1) {                       // transposed store (kT or vT)
    __hip_bfloat16* Ct = (panel == 1) ? kT : vT;
#pragma unroll
    for (int i = 0; i < 8; ++i)
#pragma unroll
      for (int j = 0; j < 4; ++j) {
        const int m0 = r0 + i * 16;
        const int nn = (c0 + j * 16) & 1023;
        const size_t row = (size_t)(((m0 >> 12) * 16 + (nn >> 6)) * 64 + (nn & 63));
        ushort4 pk;
        pk.x = f2bf(acc[i][j][0]); pk.y = f2bf(acc[i][j][1]);
        pk.z = f2bf(acc[i][j][2]); pk.w = f2bf(acc[i][j][3]);
        *(ushort4*)&Ct[row * 4096 + (m0 & 4095)] = pk;
      }
  }
  if (panel == 1) {
    // --- fused stage1: P = exp(0.125 * latent·k), psum partials ---
    // Stash roped k into dead As/Bs: head hh = w&3 (buffer), t-half = w>>2.
    // Each wave reads ONLY rows it wrote (wr half) -> intra-wave, no race.
    const int hh = w & 3;
    __hip_bfloat16* Hb = (hh < 2) ? As[hh] : Bs[hh - 2];   // [256][64] swizzled
#pragma unroll
    for (int i = 0; i < 8; ++i)
#pragma unroll
      for (int j = 0; j < 4; ++j)
#pragma unroll
        for (int r = 0; r < 4; ++r) {
          const int tl = wr + lg * 4 + i * 16 + r;   // 0..255 (this wave: wr half)
          const int d  = lr + j * 16;                // 0..63
          Hb[tl * 64 + ((((d >> 3) ^ (tl & 7)) << 3) | (d & 7))] =
              __float2bfloat16(acc[i][j][r]);
        }
    __syncthreads();
    const int hg = ((colB0 & 1023) >> 6) + hh;       // global head
    const int b  = rowA0 >> 12;
    const int t0 = rowA0 & 4095;                     // multiple of 256
    const int bh = b * 16 + hg;
    short8 la[4][2];
#pragma unroll
    for (int n = 0; n < 4; ++n)
#pragma unroll
      for (int s = 0; s < 2; ++s) {
        const float* lp = &latent[((size_t)hg * 64 + n * 16 + lr) * 64 + s * 32 + lg * 8];
        short8 f;
#pragma unroll
        for (int j = 0; j < 8; ++j) f[j] = (short)f2bf(lp[j]);
        la[n][s] = f;
      }
    float sm2[16];
#pragma unroll
    for (int i = 0; i < 16; ++i) sm2[i] = 0.f;
    const int thalf = (w >> 2) * 128;
    for (int tt2 = 0; tt2 < 8; ++tt2) {
      const int tl = thalf + tt2 * 16 + lr;
      const short8 kf0 = *(const short8*)&Hb[tl * 64 + (((0 + lg) ^ (tl & 7)) << 3)];
      const short8 kf1 = *(const short8*)&Hb[tl * 64 + (((4 + lg) ^ (tl & 7)) << 3)];
      const bool live = (mask[b * 4096 + t0 + tl] != 0);
      f32x4 a2[4];
#pragma unroll
      for (int n = 0; n < 4; ++n) {
        a2[n] = ZERO4;
        a2[n] = mfma16(la[n][0], kf0, a2[n]);
        a2[n] = mfma16(la[n][1], kf1, a2[n]);
      }
#pragma unroll
      for (int n = 0; n < 4; ++n)
#pragma unroll
        for (int r = 0; r < 4; ++r) {
          const float e = live ? __expf(a2[n][r] * 0.125f) : 0.f;
          const int m = n * 16 + lg * 4 + r;
          ((unsigned short*)P)[((size_t)bh * 64 + m) * 4096 + t0 + tl] = f2bf(e);
          sm2[n * 4 + r] += e;
        }
    }
#pragma unroll
    for (int o = 1; o < 16; o <<= 1)
#pragma unroll
      for (int i = 0; i < 16; ++i) sm2[i] += __shfl_xor(sm2[i], o, 64);
    if (lr == 0) {
      const int pchunk = (t0 >> 8) * 2 + (w >> 2);   // 0..31
      const size_t pb = ((size_t)bh * 32 + pchunk) * 64;
#pragma unroll
      for (int n = 0; n < 4; ++n)
#pragma unroll
        for (int r = 0; r < 4; ++r)
          psum[pb + n * 16 + lg * 4 + r] = sm2[n * 4 + r];
    }
  }
}

// ---------------------------------------------------------------- final GEMM (f32 out)
__global__ __launch_bounds__(512, 2)
void gemm_out(const __hip_bfloat16* __restrict__ A,
              const __hip_bfloat16* __restrict__ Bt,
              float* __restrict__ Cout) {
  GEMM_CORE(A, Bt, 1024)
  const int r0 = rowA0 + wr + lg * 4;
  const int c0 = colB0 + wc + lr;
#pragma unroll
  for (int i = 0; i < 8; ++i)
#pragma unroll
    for (int j = 0; j < 4; ++j)
#pragma unroll
      for (int r = 0; r < 4; ++r)
        Cout[(size_t)(r0 + i * 16 + r) * 1024 + (c0 + j * 16)] = acc[i][j][r];
}

// ---------------------------------------------------------------- latent GEMM v7
// Direct-from-global register-fragment MFMA reduction on unnormalized P.
// 16 slices of 256 t; grid (bh=64, 4); wave w covers slice blockIdx.y*4+w.
__global__ __launch_bounds__(256)
void latgemm7(const __hip_bfloat16* __restrict__ P,   // exp-logits [bh][64][4096]
              const __hip_bfloat16* __restrict__ kT,
              const __hip_bfloat16* __restrict__ vT,
              float* __restrict__ partials) {   // [slice(16)][bh][8192]
  const int bh = blockIdx.x;
  const int tid = threadIdx.x, w = tid >> 6, l = tid & 63;
  const int slice = blockIdx.y * 4 + w;
  const int lr = l & 15;            // frag row
  const int lk = (l >> 4) * 8;      // frag k-offset
  const size_t base = (size_t)bh * 64 * 4096;
  f32x4 ak[4][4], av[4][4];
#pragma unroll
  for (int i = 0; i < 4; ++i)
#pragma unroll
    for (int j = 0; j < 4; ++j) { ak[i][j] = ZERO4; av[i][j] = ZERO4; }
  for (int ks = 0; ks < 8; ++ks) {
    const int t = slice * 256 + ks * 32 + lk;
    short8 fp[4], fk[4], fv[4];
#pragma unroll
    for (int i = 0; i < 4; ++i) {
      const size_t ro = base + (size_t)(i * 16 + lr) * 4096 + t;
      fp[i] = *(const short8*)&P[ro];
      fk[i] = *(const short8*)&kT[ro];
      fv[i] = *(const short8*)&vT[ro];
    }
#pragma unroll
    for (int i = 0; i < 4; ++i)
#pragma unroll
      for (int j = 0; j < 4; ++j) {
        ak[i][j] = mfma16(fp[i], fk[j], ak[i][j]);   // C[m][d]
        av[i][j] = mfma16(fv[i], fp[j], av[i][j]);   // C[d][m]
      }
  }
  float* pk = partials + ((size_t)(slice * 64 + bh)) * 8192;
#pragma unroll
  for (int i = 0; i < 4; ++i)
#pragma unroll
    for (int j = 0; j < 4; ++j)
#pragma unroll
      for (int r = 0; r < 4; ++r) {
        const int row = i * 16 + 4 * (l >> 4) + r;
        const int col = j * 16 + lr;
        pk[(size_t)row * 64 + col]        = ak[i][j][r];
        pk[4096 + (size_t)row * 64 + col] = av[i][j][r];
      }
}

// Sum 16 slice-partials, normalize (cinv computed per block from psum) ->
// bf16 k_lat [bh][m][d], v_latT [bh][d][m]
__global__ void latreduce2(const float* __restrict__ partials,
                           const float* __restrict__ psum,
                           __hip_bfloat16* __restrict__ k_lat,
                           __hip_bfloat16* __restrict__ v_latT) {
  __shared__ float sci[64];
  const int bid = blockIdx.x;          // 2048 blocks; 32 per bh
  const int bh = bid >> 5;
  const int tid = threadIdx.x;
  if (tid < 64) {
    float s = 0.f;
#pragma unroll
    for (int c = 0; c < 32; ++c)
      s += psum[((size_t)bh * 32 + c) * 64 + tid];
    sci[tid] = 1.f / s;
  }
  __syncthreads();
  const int i = bid * 256 + tid;       // 524288 total
  const int off = i & 8191;
  float sm = 0.f;
#pragma unroll
  for (int c = 0; c < 16; ++c)
    sm += partials[((size_t)(c * 64 + bh)) * 8192 + off];
  const int m = (off < 4096) ? (off >> 6) : (off & 63);
  sm *= sci[m];
  if (off < 4096) k_lat[(size_t)bh * 4096 + off] = __float2bfloat16(sm);
  else            v_latT[(size_t)bh * 4096 + (off - 4096)] = __float2bfloat16(sm);
}

// ---------------------------------------------------------------- stage2 fused
__global__ __launch_bounds__(256)
void stage2_attn(const __hip_bfloat16* __restrict__ q,
                 const __hip_bfloat16* __restrict__ k_lat,
                 const __hip_bfloat16* __restrict__ v_latT,
                 __hip_bfloat16* __restrict__ attn) {
  __shared__ unsigned short Pl[4][16][64];
  const int bid = blockIdx.x;
  const int bh = bid >> 6, tt = (bid & 63) * 64;
  const int b = bh >> 4, h = bh & 15;
  const int tid = threadIdx.x, w = tid >> 6, l = tid & 63;
  const size_t qoff = ((size_t)(b * 4096 + tt + w * 16 + (l & 15)) * 16 + h) * 64;
  const short8 a0 = *(const short8*)&q[qoff + (l >> 4) * 8];
  const short8 a1 = *(const short8*)&q[qoff + 32 + (l >> 4) * 8];
  f32x4 att[4];
#pragma unroll
  for (int n = 0; n < 4; ++n) att[n] = ZERO4;
#pragma unroll
  for (int n = 0; n < 4; ++n) {
    const __hip_bfloat16* kl = &k_lat[((size_t)bh * 64 + n * 16 + (l & 15)) * 64];
    const short8 b0 = *(const short8*)&kl[(l >> 4) * 8];
    const short8 b1 = *(const short8*)&kl[32 + (l >> 4) * 8];
    att[n] = mfma16(a0, b0, att[n]);
    att[n] = mfma16(a1, b1, att[n]);
  }
  float p[4][4];
#pragma unroll
  for (int r = 0; r < 4; ++r) {
    const float v0 = att[0][r] * 0.125f, v1 = att[1][r] * 0.125f;
    const float v2 = att[2][r] * 0.125f, v3 = att[3][r] * 0.125f;
    float mxv = fmaxf(fmaxf(v0, v1), fmaxf(v2, v3));
#pragma unroll
    for (int o = 1; o < 16; o <<= 1) mxv = fmaxf(mxv, __shfl_xor(mxv, o, 64));
    const float e0 = __expf(v0 - mxv), e1 = __expf(v1 - mxv);
    const float e2 = __expf(v2 - mxv), e3 = __expf(v3 - mxv);
    float sum = e0 + e1 + e2 + e3;
#pragma unroll
    for (int o = 1; o < 16; o <<= 1) sum += __shfl_xor(sum, o, 64);
    const float inv = 1.f / sum;
    p[0][r] = e0 * inv; p[1][r] = e1 * inv; p[2][r] = e2 * inv; p[3][r] = e3 * inv;
  }
#pragma unroll
  for (int n = 0; n < 4; ++n)
#pragma unroll
    for (int r = 0; r < 4; ++r) {
      const int row = 4 * (l >> 4) + r;
      const int col = n * 16 + (l & 15);
      Pl[w][row][col ^ ((row & 7) << 3)] = f2bf(p[n][r]);
    }
  __syncthreads();
  const int arow = l & 15;
  const short8 pa0 = *(const short8*)&Pl[w][arow][(((l >> 4) + 0) ^ (arow & 7)) * 8];
  const short8 pa1 = *(const short8*)&Pl[w][arow][(((l >> 4) + 4) ^ (arow & 7)) * 8];
  f32x4 ov[4];
#pragma unroll
  for (int n = 0; n < 4; ++n) ov[n] = ZERO4;
#pragma unroll
  for (int n = 0; n < 4; ++n) {
    const __hip_bfloat16* vt = &v_latT[((size_t)bh * 64 + n * 16 + (l & 15)) * 64];
    const short8 b0 = *(const short8*)&vt[(l >> 4) * 8];
    const short8 b1 = *(const short8*)&vt[32 + (l >> 4) * 8];
    ov[n] = mfma16(pa0, b0, ov[n]);
    ov[n] = mfma16(pa1, b1, ov[n]);
  }
#pragma unroll
  for (int n = 0; n < 4; ++n) {
    const int d = n * 16 + (l & 15);
#pragma unroll
    for (int r = 0; r < 4; ++r) {
      const int trow = tt + w * 16 + 4 * (l >> 4) + r;
      attn[((size_t)(b * 4096 + trow) * 16 + h) * 64 + d] = __float2bfloat16(ov[n][r]);
    }
  }
}

// ---------------------------------------------------------------- launch
extern "C" void kernel_launch(void* const* d_in, const int* in_sizes, int n_in,
                              void* d_out, int out_size, void* d_ws, size_t ws_size,
                              hipStream_t stream) {
  const float* x      = (const float*)d_in[0];
  const float* Wq     = (const float*)d_in[1];
  const float* Wk     = (const float*)d_in[2];
  const float* Wv     = (const float*)d_in[3];
  const float* Wo     = (const float*)d_in[4];
  const float* latent = (const float*)d_in[5];
  const float* cosT   = (const float*)d_in[6];
  const float* sinT   = (const float*)d_in[7];
  const int*   mask   = (const int*)d_in[8];

  char* ws = (char*)d_ws;
  __hip_bfloat16* xb = (__hip_bfloat16*)ws;                        // 33.5MB (reused as partials)
  __hip_bfloat16* Wb = (__hip_bfloat16*)(ws + 33554432);           // 8.4MB
  __hip_bfloat16* qb = (__hip_bfloat16*)(ws + 41943040);           // 33.5MB (reused as attn)
  __hip_bfloat16* kb = (__hip_bfloat16*)(ws + 75497472);           // 33.5MB = P (exp-logits)
  __hip_bfloat16* kT = (__hip_bfloat16*)(ws + 109051904);          // 33.5MB [bh*64+d][t]
  __hip_bfloat16* vT = (__hip_bfloat16*)(ws + 142606336);          // 33.5MB
  char* tail = ws + 176160768;
  float* psum = (float*)tail;                       // 131072 f
  __hip_bfloat16* k_lat  = (__hip_bfloat16*)(psum + 131072);   // 262144 bf16
  __hip_bfloat16* v_latT = k_lat + 262144;
  __hip_bfloat16* P = kb;                   // written by gemm_qkv (k-panel)
  float* partials = (float*)xb;             // xb dead after gemm_qkv
  __hip_bfloat16* attn = qb;                // qb dead after stage2 (in-place ok)

  cvt_all<<<20480, 256, 0, stream>>>(x, Wq, Wk, Wv, Wo, xb, Wb);

  dim3 gq(64, 12);
  gemm_qkv<<<gq, 512, 0, stream>>>(xb, Wb, qb, kT, vT, latent, mask, P, psum, cosT, sinT);

  dim3 lg(64, 4);
  latgemm7<<<lg, 256, 0, stream>>>(P, kT, vT, partials);
  latreduce2<<<2048, 256, 0, stream>>>(partials, psum, k_lat, v_latT);

  stage2_attn<<<4096, 256, 0, stream>>>(qb, k_lat, v_latT, attn);

  dim3 go(64, 4);
  gemm_out<<<go, 512, 0, stream>>>(attn, Wb + 3 * 1048576, (float*)d_out);
}